// Round 1
// baseline (1898.638 us; speedup 1.0000x reference)
//
#include <hip/hip_runtime.h>

// MPNNLSTM round 0: correct fp32 baseline.
//  Phases: deg/CSR build -> GEMM(x@W1) -> SpMM+ReLU+BNstats -> BN -> GEMM(@W2)
//          -> SpMM+ReLU+BNstats -> BN -> fused 2-layer LSTM (7 steps) -> skip S.
//  ws usage ~123 MB. All fp32; MFMA/bf16 upgrades deferred to later rounds.

#define N_TOT 140000
#define NE    2240000
#define NODES 20000
#define TWIN  7
#define CIN   8
#define HD    64
#define G4    256
#define OUTC  142
#define NT    32          // nodes per LSTM block
#define NB_SCAN 137       // ceil(140000/1024)

static __device__ __forceinline__ float sigmoidf_(float x) {
  return 1.0f / (1.0f + expf(-x));
}

__global__ __launch_bounds__(256) void k_init_deg(float* __restrict__ deg) {
  int i = blockIdx.x * 256 + threadIdx.x;
  if (i < N_TOT) deg[i] = 1.0f;   // self-loop weight
}

// src [G][K] row-major -> dst [K][G]
__global__ __launch_bounds__(256) void k_transpose(const float* __restrict__ src,
                                                   float* __restrict__ dst, int G, int K) {
  int idx = blockIdx.x * 256 + threadIdx.x;
  if (idx < G * K) {
    int k = idx / G, g = idx - k * G;
    dst[idx] = src[g * K + k];
  }
}

__global__ __launch_bounds__(256) void k_deg_cnt(const int* __restrict__ srcI,
                                                 const int* __restrict__ dstI,
                                                 const float* __restrict__ w,
                                                 float* deg, int* cnt) {
  int e = blockIdx.x * 256 + threadIdx.x;
  if (e < NE) {
    int d = dstI[e];
    atomicAdd(&deg[d], w[e]);
    atomicAdd(&cnt[d], 1);
  }
}

__global__ __launch_bounds__(256) void k_dinv(const float* __restrict__ deg,
                                              float* __restrict__ dinv) {
  int i = blockIdx.x * 256 + threadIdx.x;
  if (i < N_TOT) dinv[i] = rsqrtf(deg[i]);   // deg >= 1 always (self loop)
}

// ---- 3-phase exclusive scan of cnt -> rowptr (chunk = 1024) ----
__global__ __launch_bounds__(256) void k_scan_a(const int* __restrict__ cnt,
                                                int* __restrict__ bsum, int n) {
  __shared__ int sd[256];
  int b = blockIdx.x, t = threadIdx.x;
  int s = 0;
  for (int i = t; i < 1024; i += 256) {
    int idx = b * 1024 + i;
    s += (idx < n) ? cnt[idx] : 0;
  }
  sd[t] = s; __syncthreads();
  for (int off = 128; off > 0; off >>= 1) {
    if (t < off) sd[t] += sd[t + off];
    __syncthreads();
  }
  if (t == 0) bsum[b] = sd[0];
}

__global__ __launch_bounds__(64) void k_scan_b(int* __restrict__ bsum, int nb) {
  if (threadIdx.x == 0 && blockIdx.x == 0) {
    int acc = 0;
    for (int i = 0; i < nb; ++i) { int v = bsum[i]; bsum[i] = acc; acc += v; }
  }
}

__global__ __launch_bounds__(256) void k_scan_c(const int* __restrict__ cnt,
                                                const int* __restrict__ bsum,
                                                int* __restrict__ rowptr, int n, int etot) {
  __shared__ int tsum[256];
  int b = blockIdx.x, t = threadIdx.x;
  int base = b * 1024 + t * 4;
  int v[4]; int s = 0;
  #pragma unroll
  for (int i = 0; i < 4; ++i) { int idx = base + i; v[i] = (idx < n) ? cnt[idx] : 0; s += v[i]; }
  tsum[t] = s; __syncthreads();
  for (int off = 1; off < 256; off <<= 1) {
    int xv = 0;
    if (t >= off) xv = tsum[t - off];
    __syncthreads();
    if (t >= off) tsum[t] += xv;
    __syncthreads();
  }
  int excl = bsum[b] + ((t > 0) ? tsum[t - 1] : 0);
  #pragma unroll
  for (int i = 0; i < 4; ++i) {
    int idx = base + i;
    if (idx < n) { rowptr[idx] = excl; excl += v[i]; }
  }
  if (b == 0 && t == 0) rowptr[n] = etot;
}

__global__ __launch_bounds__(256) void k_fill(const int* __restrict__ srcI,
                                              const int* __restrict__ dstI,
                                              const float* __restrict__ w,
                                              const float* __restrict__ dinv,
                                              const int* __restrict__ rowptr,
                                              int* cursor,
                                              int* __restrict__ colA,
                                              float* __restrict__ valA) {
  int e = blockIdx.x * 256 + threadIdx.x;
  if (e < NE) {
    int s = srcI[e], d = dstI[e];
    int pos = atomicAdd(&cursor[d], 1);
    int i = rowptr[d] + pos;
    colA[i] = s;
    valA[i] = dinv[s] * w[e] * dinv[d];
  }
}

// H0 = x @ W1   ([N,8] @ [8,64]); wave per row, lane = out channel
__global__ __launch_bounds__(256) void k_gemm_in(const float* __restrict__ x,
                                                 const float* __restrict__ W1,
                                                 float* __restrict__ H0) {
  __shared__ float w[CIN * HD];
  for (int i = threadIdx.x; i < CIN * HD; i += 256) w[i] = W1[i];
  __syncthreads();
  int wid = (blockIdx.x * 256 + threadIdx.x) >> 6;
  int lane = threadIdx.x & 63;
  int nw = (gridDim.x * 256) >> 6;
  for (int n = wid; n < N_TOT; n += nw) {
    float acc = 0.f;
    #pragma unroll
    for (int c = 0; c < CIN; ++c) acc += x[n * CIN + c] * w[c * HD + lane];
    H0[n * HD + lane] = acc;
  }
}

// out[d] = relu( dinv[d]^2*Hin[d] + sum_e val*Hin[col] + bias ); accumulate BN stats
__global__ __launch_bounds__(256) void k_spmm(const float* __restrict__ Hin,
                                              const float* __restrict__ dinv,
                                              const int* __restrict__ rowptr,
                                              const int* __restrict__ colA,
                                              const float* __restrict__ valA,
                                              const float* __restrict__ bias,
                                              float* __restrict__ Aout,
                                              float* gsum, float* gsq) {
  int wid = (blockIdx.x * 256 + threadIdx.x) >> 6;
  int lane = threadIdx.x & 63;
  int nw = (gridDim.x * 256) >> 6;
  float b = bias[lane];
  float s = 0.f, q = 0.f;
  for (int d = wid; d < N_TOT; d += nw) {
    float di = dinv[d];
    float acc = di * di * Hin[d * HD + lane];
    int beg = rowptr[d], end = rowptr[d + 1];
    #pragma unroll 4
    for (int i = beg; i < end; ++i) {
      int c = colA[i];
      float v = valA[i];
      acc += v * Hin[c * HD + lane];
    }
    float r = fmaxf(acc + b, 0.f);
    Aout[d * HD + lane] = r;
    s += r; q += r * r;
  }
  atomicAdd(&gsum[lane], s);
  atomicAdd(&gsq[lane], q);
}

__global__ __launch_bounds__(64) void k_bnfin(const float* __restrict__ gsum,
                                              const float* __restrict__ gsq,
                                              const float* __restrict__ gamma,
                                              const float* __restrict__ beta,
                                              float* __restrict__ scale,
                                              float* __restrict__ shift) {
  int j = threadIdx.x;
  if (j < HD) {
    float m = gsum[j] / (float)N_TOT;
    float v = gsq[j] / (float)N_TOT - m * m;
    float sc = gamma[j] * rsqrtf(v + 1e-5f);
    scale[j] = sc;
    shift[j] = beta[j] - m * sc;
  }
}

// Hb = BN1(A1) @ W2  ([N,64]@[64,64]); wave per row; W2 already [k][j] layout
__global__ __launch_bounds__(256) void k_gemm_h(const float* __restrict__ A1,
                                                const float* __restrict__ scale,
                                                const float* __restrict__ shift,
                                                const float* __restrict__ W2,
                                                float* __restrict__ Hb) {
  __shared__ float w[HD * HD];
  for (int i = threadIdx.x; i < HD * HD; i += 256) w[i] = W2[i];
  __syncthreads();
  int wid = (blockIdx.x * 256 + threadIdx.x) >> 6;
  int lane = threadIdx.x & 63;
  int nw = (gridDim.x * 256) >> 6;
  float sc = scale[lane], sh = shift[lane];
  for (int n = wid; n < N_TOT; n += nw) {
    float xj = sc * A1[n * HD + lane] + sh;
    float acc = 0.f;
    #pragma unroll 8
    for (int k = 0; k < HD; ++k) acc += __shfl(xj, k, 64) * w[k * HD + lane];
    Hb[n * HD + lane] = acc;
  }
}

// Fused 2-layer LSTM over 7 steps. Block owns NT nodes; thread t = gate column.
// Weights pre-transposed to [k][256] (coalesced, L2-resident).
__global__ __launch_bounds__(256) void k_lstm(const float* __restrict__ A1,
                                              const float* __restrict__ A2,
                                              const float* __restrict__ scale1,
                                              const float* __restrict__ shift1,
                                              const float* __restrict__ scale2,
                                              const float* __restrict__ shift2,
                                              const float* __restrict__ WtIH1,
                                              const float* __restrict__ WtHH1,
                                              const float* __restrict__ WtIH2,
                                              const float* __restrict__ WtHH2,
                                              const float* __restrict__ bih1,
                                              const float* __restrict__ bhh1,
                                              const float* __restrict__ bih2,
                                              const float* __restrict__ bhh2,
                                              float* __restrict__ out) {
  __shared__ float xs[NT][128];     // Xc tile (BN applied)
  __shared__ float hs[NT][HD];      // h1
  __shared__ float h2s[NT][HD];     // h2
  __shared__ float gates[NT][G4];
  int t = threadIdx.x;
  int n0 = blockIdx.x * NT;

  for (int i = t; i < NT * HD; i += 256) {
    (&hs[0][0])[i] = 0.f;
    (&h2s[0][0])[i] = 0.f;
  }
  float c1[NT * HD / 256], c2[NT * HD / 256];
  #pragma unroll
  for (int r = 0; r < NT * HD / 256; ++r) { c1[r] = 0.f; c2[r] = 0.f; }
  float bs1 = bih1[t] + bhh1[t];
  float bs2 = bih2[t] + bhh2[t];
  __syncthreads();

  float acc[NT];
  for (int step = 0; step < TWIN; ++step) {
    // stage Xc tile = [BN1(A1) | BN2(A2)] for supra-nodes step*NODES + n0 + n
    for (int i = t; i < NT * 128; i += 256) {
      int n = i >> 7, k = i & 127;
      int sn = step * NODES + n0 + n;
      float v;
      if (k < HD) v = scale1[k] * A1[sn * HD + k] + shift1[k];
      else        v = scale2[k - HD] * A2[sn * HD + (k - HD)] + shift2[k - HD];
      xs[n][k] = v;
    }
    __syncthreads();

    // gates1 = bs1 + xs @ WtIH1 + h1_prev @ WtHH1
    #pragma unroll
    for (int n = 0; n < NT; ++n) acc[n] = bs1;
    for (int k = 0; k < 128; k += 2) {
      float w0 = WtIH1[k * G4 + t];
      float w1 = WtIH1[(k + 1) * G4 + t];
      #pragma unroll
      for (int n = 0; n < NT; ++n) {
        float2 x2 = *reinterpret_cast<const float2*>(&xs[n][k]);
        acc[n] = fmaf(x2.y, w1, fmaf(x2.x, w0, acc[n]));
      }
    }
    for (int k = 0; k < HD; k += 2) {
      float w0 = WtHH1[k * G4 + t];
      float w1 = WtHH1[(k + 1) * G4 + t];
      #pragma unroll
      for (int n = 0; n < NT; ++n) {
        float2 h2v = *reinterpret_cast<const float2*>(&hs[n][k]);
        acc[n] = fmaf(h2v.y, w1, fmaf(h2v.x, w0, acc[n]));
      }
    }
    #pragma unroll
    for (int n = 0; n < NT; ++n) gates[n][t] = acc[n];
    __syncthreads();

    // cell/output update LSTM1 (PyTorch gate order i,f,g,o)
    #pragma unroll
    for (int r = 0; r < NT * HD / 256; ++r) {
      int i = t + 256 * r;
      int n = i >> 6, j = i & 63;
      float gi = gates[n][j], gf = gates[n][HD + j];
      float gg = gates[n][2 * HD + j], go = gates[n][3 * HD + j];
      float c = sigmoidf_(gf) * c1[r] + sigmoidf_(gi) * tanhf(gg);
      c1[r] = c;
      float h = sigmoidf_(go) * tanhf(c);
      hs[n][j] = h;
      if (step == TWIN - 1) out[(size_t)(n0 + n) * OUTC + j] = h;
    }
    __syncthreads();

    // gates2 = bs2 + h1 @ WtIH2 + h2_prev @ WtHH2
    #pragma unroll
    for (int n = 0; n < NT; ++n) acc[n] = bs2;
    for (int k = 0; k < HD; k += 2) {
      float w0 = WtIH2[k * G4 + t];
      float w1 = WtIH2[(k + 1) * G4 + t];
      #pragma unroll
      for (int n = 0; n < NT; ++n) {
        float2 hv = *reinterpret_cast<const float2*>(&hs[n][k]);
        acc[n] = fmaf(hv.y, w1, fmaf(hv.x, w0, acc[n]));
      }
    }
    for (int k = 0; k < HD; k += 2) {
      float w0 = WtHH2[k * G4 + t];
      float w1 = WtHH2[(k + 1) * G4 + t];
      #pragma unroll
      for (int n = 0; n < NT; ++n) {
        float2 hv = *reinterpret_cast<const float2*>(&h2s[n][k]);
        acc[n] = fmaf(hv.y, w1, fmaf(hv.x, w0, acc[n]));
      }
    }
    #pragma unroll
    for (int n = 0; n < NT; ++n) gates[n][t] = acc[n];
    __syncthreads();

    // cell/output update LSTM2
    #pragma unroll
    for (int r = 0; r < NT * HD / 256; ++r) {
      int i = t + 256 * r;
      int n = i >> 6, j = i & 63;
      float gi = gates[n][j], gf = gates[n][HD + j];
      float gg = gates[n][2 * HD + j], go = gates[n][3 * HD + j];
      float c = sigmoidf_(gf) * c2[r] + sigmoidf_(gi) * tanhf(gg);
      c2[r] = c;
      float h = sigmoidf_(go) * tanhf(c);
      h2s[n][j] = h;
      if (step == TWIN - 1) out[(size_t)(n0 + n) * OUTC + HD + j] = h;
    }
    __syncthreads();
  }
}

// skip connection S -> out cols 128..141
__global__ __launch_bounds__(256) void k_out_s(const float* __restrict__ x,
                                               float* __restrict__ out) {
  int idx = blockIdx.x * 256 + threadIdx.x;
  if (idx < NODES * 14) {
    int n = idx / 14, c = idx - n * 14;
    float v = (c < CIN) ? x[n * CIN + c]
                        : x[((c - (CIN - 1)) * NODES + n) * CIN + (CIN - 1)];
    out[(size_t)n * OUTC + 128 + c] = v;
  }
}

extern "C" void kernel_launch(void* const* d_in, const int* in_sizes, int n_in,
                              void* d_out, int out_size, void* d_ws, size_t ws_size,
                              hipStream_t stream) {
  const float* x      = (const float*)d_in[0];
  const int*   ei     = (const int*)d_in[1];
  const float* ew     = (const float*)d_in[2];
  const float* W1     = (const float*)d_in[3];
  const float* b1     = (const float*)d_in[4];
  const float* W2     = (const float*)d_in[5];
  const float* b2     = (const float*)d_in[6];
  const float* gamma1 = (const float*)d_in[7];
  const float* beta1  = (const float*)d_in[8];
  const float* gamma2 = (const float*)d_in[9];
  const float* beta2  = (const float*)d_in[10];
  const float* Wih1   = (const float*)d_in[11];
  const float* Whh1   = (const float*)d_in[12];
  const float* bih1   = (const float*)d_in[13];
  const float* bhh1   = (const float*)d_in[14];
  const float* Wih2   = (const float*)d_in[15];
  const float* Whh2   = (const float*)d_in[16];
  const float* bih2   = (const float*)d_in[17];
  const float* bhh2   = (const float*)d_in[18];
  const int* srcI = ei;
  const int* dstI = ei + NE;
  float* out = (float*)d_out;

  char* base = (char*)d_ws;
  size_t off = 0;
  auto alloc = [&](size_t bytes) -> void* {
    void* p = base + off;
    off = (off + bytes + 255) & ~(size_t)255;
    return p;
  };
  // persistent-ish small
  float* deg    = (float*)alloc(N_TOT * 4);
  float* dinv   = (float*)alloc(N_TOT * 4);
  int*   rowptr = (int*)alloc((N_TOT + 1) * 4);
  int*   bsum   = (int*)alloc(NB_SCAN * 4);
  float* WtIH1  = (float*)alloc(128 * G4 * 4);
  float* WtHH1  = (float*)alloc(HD * G4 * 4);
  float* WtIH2  = (float*)alloc(HD * G4 * 4);
  float* WtHH2  = (float*)alloc(HD * G4 * 4);
  float* scale1 = (float*)alloc(HD * 4);
  float* shift1 = (float*)alloc(HD * 4);
  float* scale2 = (float*)alloc(HD * 4);
  float* shift2 = (float*)alloc(HD * 4);
  // zeroed-every-call region (must stay contiguous)
  char* zstart = base + off;
  int*   cnt    = (int*)alloc(N_TOT * 4);
  int*   cursor = (int*)alloc(N_TOT * 4);
  float* sum1   = (float*)alloc(HD * 4);
  float* sq1    = (float*)alloc(HD * 4);
  float* sum2   = (float*)alloc(HD * 4);
  float* sq2    = (float*)alloc(HD * 4);
  size_t zbytes = (size_t)((base + off) - zstart);
  // big buffers
  int*   colA = (int*)alloc((size_t)NE * 4);
  float* valA = (float*)alloc((size_t)NE * 4);
  float* H0   = (float*)alloc((size_t)N_TOT * HD * 4);   // also reused as Hb
  float* A1   = (float*)alloc((size_t)N_TOT * HD * 4);
  float* A2   = (float*)alloc((size_t)N_TOT * HD * 4);
  // total ~123 MB

  hipMemsetAsync(zstart, 0, zbytes, stream);
  k_init_deg<<<(N_TOT + 255) / 256, 256, 0, stream>>>(deg);
  k_transpose<<<(G4 * 128 + 255) / 256, 256, 0, stream>>>(Wih1, WtIH1, G4, 128);
  k_transpose<<<(G4 * HD + 255) / 256, 256, 0, stream>>>(Whh1, WtHH1, G4, HD);
  k_transpose<<<(G4 * HD + 255) / 256, 256, 0, stream>>>(Wih2, WtIH2, G4, HD);
  k_transpose<<<(G4 * HD + 255) / 256, 256, 0, stream>>>(Whh2, WtHH2, G4, HD);
  k_deg_cnt<<<(NE + 255) / 256, 256, 0, stream>>>(srcI, dstI, ew, deg, cnt);
  k_dinv<<<(N_TOT + 255) / 256, 256, 0, stream>>>(deg, dinv);
  k_scan_a<<<NB_SCAN, 256, 0, stream>>>(cnt, bsum, N_TOT);
  k_scan_b<<<1, 64, 0, stream>>>(bsum, NB_SCAN);
  k_scan_c<<<NB_SCAN, 256, 0, stream>>>(cnt, bsum, rowptr, N_TOT, NE);
  k_fill<<<(NE + 255) / 256, 256, 0, stream>>>(srcI, dstI, ew, dinv, rowptr, cursor, colA, valA);
  k_gemm_in<<<512, 256, 0, stream>>>(x, W1, H0);
  k_spmm<<<1024, 256, 0, stream>>>(H0, dinv, rowptr, colA, valA, b1, A1, sum1, sq1);
  k_bnfin<<<1, 64, 0, stream>>>(sum1, sq1, gamma1, beta1, scale1, shift1);
  k_gemm_h<<<512, 256, 0, stream>>>(A1, scale1, shift1, W2, H0);
  k_spmm<<<1024, 256, 0, stream>>>(H0, dinv, rowptr, colA, valA, b2, A2, sum2, sq2);
  k_bnfin<<<1, 64, 0, stream>>>(sum2, sq2, gamma2, beta2, scale2, shift2);
  k_lstm<<<NODES / NT, 256, 0, stream>>>(A1, A2, scale1, shift1, scale2, shift2,
                                         WtIH1, WtHH1, WtIH2, WtHH2,
                                         bih1, bhh1, bih2, bhh2, out);
  k_out_s<<<(NODES * 14 + 255) / 256, 256, 0, stream>>>(x, out);
}

// Round 2
// 1283.443 us; speedup vs baseline: 1.4793x; 1.4793x over previous
//
#include <hip/hip_runtime.h>

// MPNNLSTM round 1: LSTM gates on bf16 MFMA (fused persistent kernel).
//  Graph phase unchanged from round 0 (next target once profiled).

#define N_TOT 140000
#define NE    2240000
#define NODES 20000
#define TWIN  7
#define CIN   8
#define HD    64
#define OUTC  142
#define NB_SCAN 137       // ceil(140000/1024)

typedef __attribute__((ext_vector_type(8))) short short8;
typedef __attribute__((ext_vector_type(4))) float f32x4;

static __device__ __forceinline__ float sigmoidf_(float x) {
  return 1.0f / (1.0f + expf(-x));
}
static __device__ __forceinline__ ushort f2bf(float x) {
  union { float f; uint32_t u; } c; c.f = x;
  uint32_t r = c.u + 0x7fff + ((c.u >> 16) & 1);   // RNE
  return (ushort)(r >> 16);
}
static __device__ __forceinline__ float bf2f(ushort h) {
  union { uint32_t u; float f; } c; c.u = ((uint32_t)h) << 16; return c.f;
}

__global__ __launch_bounds__(256) void k_init_deg(float* __restrict__ deg) {
  int i = blockIdx.x * 256 + threadIdx.x;
  if (i < N_TOT) deg[i] = 1.0f;   // self-loop weight
}

// Pack W [256][K] (row-major f32, PyTorch [4H, in]) into MFMA B-fragment order:
// Wp[((kc*16 + nt)*64 + lane)*8 + j] = bf16( W[nt*16 + (lane&15)][kc*32 + (lane>>4)*8 + j] )
__global__ __launch_bounds__(256) void k_pack(const float* __restrict__ W,
                                              ushort* __restrict__ Wp, int K) {
  int idx = blockIdx.x * 256 + threadIdx.x;
  int total = (K >> 5) * 16 * 64 * 8;
  if (idx < total) {
    int j = idx & 7, lane = (idx >> 3) & 63, nt = (idx >> 9) & 15, kc = idx >> 13;
    int g = nt * 16 + (lane & 15);
    int k = kc * 32 + ((lane >> 4) << 3) + j;
    Wp[idx] = f2bf(W[g * K + k]);
  }
}

__global__ __launch_bounds__(256) void k_bsum(const float* __restrict__ bih1,
                                              const float* __restrict__ bhh1,
                                              const float* __restrict__ bih2,
                                              const float* __restrict__ bhh2,
                                              float* __restrict__ bsum1,
                                              float* __restrict__ bsum2) {
  int t = threadIdx.x;
  if (blockIdx.x == 0) bsum1[t] = bih1[t] + bhh1[t];
  else                 bsum2[t] = bih2[t] + bhh2[t];
}

__global__ __launch_bounds__(256) void k_deg_cnt(const int* __restrict__ srcI,
                                                 const int* __restrict__ dstI,
                                                 const float* __restrict__ w,
                                                 float* deg, int* cnt) {
  int e = blockIdx.x * 256 + threadIdx.x;
  if (e < NE) {
    int d = dstI[e];
    atomicAdd(&deg[d], w[e]);
    atomicAdd(&cnt[d], 1);
  }
}

__global__ __launch_bounds__(256) void k_dinv(const float* __restrict__ deg,
                                              float* __restrict__ dinv) {
  int i = blockIdx.x * 256 + threadIdx.x;
  if (i < N_TOT) dinv[i] = rsqrtf(deg[i]);
}

// ---- 3-phase exclusive scan of cnt -> rowptr (chunk = 1024) ----
__global__ __launch_bounds__(256) void k_scan_a(const int* __restrict__ cnt,
                                                int* __restrict__ bsum, int n) {
  __shared__ int sd[256];
  int b = blockIdx.x, t = threadIdx.x;
  int s = 0;
  for (int i = t; i < 1024; i += 256) {
    int idx = b * 1024 + i;
    s += (idx < n) ? cnt[idx] : 0;
  }
  sd[t] = s; __syncthreads();
  for (int off = 128; off > 0; off >>= 1) {
    if (t < off) sd[t] += sd[t + off];
    __syncthreads();
  }
  if (t == 0) bsum[b] = sd[0];
}

__global__ __launch_bounds__(64) void k_scan_b(int* __restrict__ bsum, int nb) {
  if (threadIdx.x == 0 && blockIdx.x == 0) {
    int acc = 0;
    for (int i = 0; i < nb; ++i) { int v = bsum[i]; bsum[i] = acc; acc += v; }
  }
}

__global__ __launch_bounds__(256) void k_scan_c(const int* __restrict__ cnt,
                                                const int* __restrict__ bsum,
                                                int* __restrict__ rowptr, int n, int etot) {
  __shared__ int tsum[256];
  int b = blockIdx.x, t = threadIdx.x;
  int base = b * 1024 + t * 4;
  int v[4]; int s = 0;
  #pragma unroll
  for (int i = 0; i < 4; ++i) { int idx = base + i; v[i] = (idx < n) ? cnt[idx] : 0; s += v[i]; }
  tsum[t] = s; __syncthreads();
  for (int off = 1; off < 256; off <<= 1) {
    int xv = 0;
    if (t >= off) xv = tsum[t - off];
    __syncthreads();
    if (t >= off) tsum[t] += xv;
    __syncthreads();
  }
  int excl = bsum[b] + ((t > 0) ? tsum[t - 1] : 0);
  #pragma unroll
  for (int i = 0; i < 4; ++i) {
    int idx = base + i;
    if (idx < n) { rowptr[idx] = excl; excl += v[i]; }
  }
  if (b == 0 && t == 0) rowptr[n] = etot;
}

__global__ __launch_bounds__(256) void k_fill(const int* __restrict__ srcI,
                                              const int* __restrict__ dstI,
                                              const float* __restrict__ w,
                                              const float* __restrict__ dinv,
                                              const int* __restrict__ rowptr,
                                              int* cursor,
                                              int* __restrict__ colA,
                                              float* __restrict__ valA) {
  int e = blockIdx.x * 256 + threadIdx.x;
  if (e < NE) {
    int s = srcI[e], d = dstI[e];
    int pos = atomicAdd(&cursor[d], 1);
    int i = rowptr[d] + pos;
    colA[i] = s;
    valA[i] = dinv[s] * w[e] * dinv[d];
  }
}

// H0 = x @ W1   ([N,8] @ [8,64]); wave per row, lane = out channel
__global__ __launch_bounds__(256) void k_gemm_in(const float* __restrict__ x,
                                                 const float* __restrict__ W1,
                                                 float* __restrict__ H0) {
  __shared__ float w[CIN * HD];
  for (int i = threadIdx.x; i < CIN * HD; i += 256) w[i] = W1[i];
  __syncthreads();
  int wid = (blockIdx.x * 256 + threadIdx.x) >> 6;
  int lane = threadIdx.x & 63;
  int nw = (gridDim.x * 256) >> 6;
  for (int n = wid; n < N_TOT; n += nw) {
    float acc = 0.f;
    #pragma unroll
    for (int c = 0; c < CIN; ++c) acc += x[n * CIN + c] * w[c * HD + lane];
    H0[n * HD + lane] = acc;
  }
}

// out[d] = relu( dinv[d]^2*Hin[d] + sum_e val*Hin[col] + bias ); accumulate BN stats
__global__ __launch_bounds__(256) void k_spmm(const float* __restrict__ Hin,
                                              const float* __restrict__ dinv,
                                              const int* __restrict__ rowptr,
                                              const int* __restrict__ colA,
                                              const float* __restrict__ valA,
                                              const float* __restrict__ bias,
                                              float* __restrict__ Aout,
                                              float* gsum, float* gsq) {
  int wid = (blockIdx.x * 256 + threadIdx.x) >> 6;
  int lane = threadIdx.x & 63;
  int nw = (gridDim.x * 256) >> 6;
  float b = bias[lane];
  float s = 0.f, q = 0.f;
  for (int d = wid; d < N_TOT; d += nw) {
    float di = dinv[d];
    float acc = di * di * Hin[d * HD + lane];
    int beg = rowptr[d], end = rowptr[d + 1];
    #pragma unroll 4
    for (int i = beg; i < end; ++i) {
      int c = colA[i];
      float v = valA[i];
      acc += v * Hin[c * HD + lane];
    }
    float r = fmaxf(acc + b, 0.f);
    Aout[d * HD + lane] = r;
    s += r; q += r * r;
  }
  atomicAdd(&gsum[lane], s);
  atomicAdd(&gsq[lane], q);
}

__global__ __launch_bounds__(64) void k_bnfin(const float* __restrict__ gsum,
                                              const float* __restrict__ gsq,
                                              const float* __restrict__ gamma,
                                              const float* __restrict__ beta,
                                              float* __restrict__ scale,
                                              float* __restrict__ shift) {
  int j = threadIdx.x;
  if (j < HD) {
    float m = gsum[j] / (float)N_TOT;
    float v = gsq[j] / (float)N_TOT - m * m;
    float sc = gamma[j] * rsqrtf(v + 1e-5f);
    scale[j] = sc;
    shift[j] = beta[j] - m * sc;
  }
}

// Hb = BN1(A1) @ W2  ([N,64]@[64,64]); wave per row; W2 is [k][j] layout
__global__ __launch_bounds__(256) void k_gemm_h(const float* __restrict__ A1,
                                                const float* __restrict__ scale,
                                                const float* __restrict__ shift,
                                                const float* __restrict__ W2,
                                                float* __restrict__ Hb) {
  __shared__ float w[HD * HD];
  for (int i = threadIdx.x; i < HD * HD; i += 256) w[i] = W2[i];
  __syncthreads();
  int wid = (blockIdx.x * 256 + threadIdx.x) >> 6;
  int lane = threadIdx.x & 63;
  int nw = (gridDim.x * 256) >> 6;
  float sc = scale[lane], sh = shift[lane];
  for (int n = wid; n < N_TOT; n += nw) {
    float xj = sc * A1[n * HD + lane] + sh;
    float acc = 0.f;
    #pragma unroll 8
    for (int k = 0; k < HD; ++k) acc += __shfl(xj, k, 64) * w[k * HD + lane];
    Hb[n * HD + lane] = acc;
  }
}

// ---------------------------------------------------------------------------
// Fused 2-layer LSTM, MFMA gates. Block = 256 threads (4 waves), 32 nodes.
// Wave w: gate rows m0=(w&1)*16, gate cols [(w>>1)*128, +128) -> 8 n-tiles.
// Per step: stage Xc (BN'd, bf16) -> gates1 = Xc@Wp1 + h1@Wphh1 + bsum1 (MFMA)
//           -> update h1,c1 -> gates2 = h1@Wpih2 + h2@Wphh2 + bsum2 -> update.
// ---------------------------------------------------------------------------
__global__ __launch_bounds__(256) void k_lstm2(const float* __restrict__ A1,
                                               const float* __restrict__ A2,
                                               const float* __restrict__ scale1,
                                               const float* __restrict__ shift1,
                                               const float* __restrict__ scale2,
                                               const float* __restrict__ shift2,
                                               const ushort* __restrict__ Wp1,
                                               const ushort* __restrict__ Wphh1,
                                               const ushort* __restrict__ Wpih2,
                                               const ushort* __restrict__ Wphh2,
                                               const float* __restrict__ bsum1,
                                               const float* __restrict__ bsum2,
                                               float* __restrict__ out) {
  __shared__ ushort xs[32 * 136];    // Xc tile, bf16, padded stride 136
  __shared__ ushort h1s[32 * 72];    // h1, bf16, padded stride 72
  __shared__ ushort h2s[32 * 72];    // h2
  __shared__ float  gates[32 * 256];
  int t = threadIdx.x;
  int n0 = blockIdx.x * 32;
  int wid = t >> 6, lane = t & 63;
  int m0 = (wid & 1) * 16;
  int ntg0 = (wid >> 1) * 8;                     // this wave's n-tile base
  int aoffX = (m0 + (lane & 15)) * 136 + ((lane >> 4) << 3);
  int aoffH = (m0 + (lane & 15)) * 72 + ((lane >> 4) << 3);
  int drow0 = m0 + ((lane >> 4) << 2);           // gate-write row (0..31)
  int dcol = lane & 15;
  int ej = t & 63;                               // elementwise: j = t&63
  int en0 = t >> 6;                              // node = en0 + 4r
  float c1[8], c2[8];
  #pragma unroll
  for (int r = 0; r < 8; ++r) { c1[r] = 0.f; c2[r] = 0.f; }

  for (int step = 0; step < TWIN; ++step) {
    // ---- stage Xc = [BN1(A1) | BN2(A2)] for rows n0..n0+31 of this step
    for (int i = t; i < 32 * 128; i += 256) {
      int r = i >> 7, k = i & 127;
      int sn = step * NODES + n0 + r;
      float v;
      if (k < HD) v = scale1[k] * A1[(size_t)sn * HD + k] + shift1[k];
      else { int kk = k - HD; v = scale2[kk] * A2[(size_t)sn * HD + kk] + shift2[kk]; }
      xs[r * 136 + k] = f2bf(v);
    }
    __syncthreads();

    // ---- layer-1 gates (MFMA): Xc @ Wp1 (K=128) + h1 @ Wphh1 (K=64)
    f32x4 acc[8];
    #pragma unroll
    for (int i = 0; i < 8; ++i) acc[i] = (f32x4){0.f, 0.f, 0.f, 0.f};
    #pragma unroll
    for (int kc = 0; kc < 4; ++kc) {
      short8 a = *reinterpret_cast<const short8*>(&xs[aoffX + kc * 32]);
      #pragma unroll
      for (int nt = 0; nt < 8; ++nt) {
        short8 b = *reinterpret_cast<const short8*>(&Wp1[((kc * 16 + ntg0 + nt) * 64 + lane) * 8]);
        acc[nt] = __builtin_amdgcn_mfma_f32_16x16x32_bf16(a, b, acc[nt], 0, 0, 0);
      }
    }
    if (step > 0) {
      #pragma unroll
      for (int kc = 0; kc < 2; ++kc) {
        short8 a = *reinterpret_cast<const short8*>(&h1s[aoffH + kc * 32]);
        #pragma unroll
        for (int nt = 0; nt < 8; ++nt) {
          short8 b = *reinterpret_cast<const short8*>(&Wphh1[((kc * 16 + ntg0 + nt) * 64 + lane) * 8]);
          acc[nt] = __builtin_amdgcn_mfma_f32_16x16x32_bf16(a, b, acc[nt], 0, 0, 0);
        }
      }
    }
    #pragma unroll
    for (int nt = 0; nt < 8; ++nt) {
      int col = (ntg0 + nt) * 16 + dcol;
      float bb = bsum1[col];
      #pragma unroll
      for (int j = 0; j < 4; ++j) gates[(drow0 + j) * 256 + col] = acc[nt][j] + bb;
    }
    __syncthreads();

    // ---- layer-1 elementwise update (gate order i,f,g,o)
    #pragma unroll
    for (int r = 0; r < 8; ++r) {
      int n = en0 + 4 * r;
      float gi = gates[n * 256 + ej],       gf = gates[n * 256 + 64 + ej];
      float gg = gates[n * 256 + 128 + ej], go = gates[n * 256 + 192 + ej];
      float c = sigmoidf_(gf) * c1[r] + sigmoidf_(gi) * tanhf(gg);
      c1[r] = c;
      float h = sigmoidf_(go) * tanhf(c);
      h1s[n * 72 + ej] = f2bf(h);
      if (step == TWIN - 1) out[(size_t)(n0 + n) * OUTC + ej] = h;
    }
    __syncthreads();

    // ---- layer-2 gates (MFMA): h1 @ Wpih2 + h2 @ Wphh2
    #pragma unroll
    for (int i = 0; i < 8; ++i) acc[i] = (f32x4){0.f, 0.f, 0.f, 0.f};
    #pragma unroll
    for (int kc = 0; kc < 2; ++kc) {
      short8 a = *reinterpret_cast<const short8*>(&h1s[aoffH + kc * 32]);
      #pragma unroll
      for (int nt = 0; nt < 8; ++nt) {
        short8 b = *reinterpret_cast<const short8*>(&Wpih2[((kc * 16 + ntg0 + nt) * 64 + lane) * 8]);
        acc[nt] = __builtin_amdgcn_mfma_f32_16x16x32_bf16(a, b, acc[nt], 0, 0, 0);
      }
    }
    if (step > 0) {
      #pragma unroll
      for (int kc = 0; kc < 2; ++kc) {
        short8 a = *reinterpret_cast<const short8*>(&h2s[aoffH + kc * 32]);
        #pragma unroll
        for (int nt = 0; nt < 8; ++nt) {
          short8 b = *reinterpret_cast<const short8*>(&Wphh2[((kc * 16 + ntg0 + nt) * 64 + lane) * 8]);
          acc[nt] = __builtin_amdgcn_mfma_f32_16x16x32_bf16(a, b, acc[nt], 0, 0, 0);
        }
      }
    }
    #pragma unroll
    for (int nt = 0; nt < 8; ++nt) {
      int col = (ntg0 + nt) * 16 + dcol;
      float bb = bsum2[col];
      #pragma unroll
      for (int j = 0; j < 4; ++j) gates[(drow0 + j) * 256 + col] = acc[nt][j] + bb;
    }
    __syncthreads();

    // ---- layer-2 elementwise update
    #pragma unroll
    for (int r = 0; r < 8; ++r) {
      int n = en0 + 4 * r;
      float gi = gates[n * 256 + ej],       gf = gates[n * 256 + 64 + ej];
      float gg = gates[n * 256 + 128 + ej], go = gates[n * 256 + 192 + ej];
      float c = sigmoidf_(gf) * c2[r] + sigmoidf_(gi) * tanhf(gg);
      c2[r] = c;
      float h = sigmoidf_(go) * tanhf(c);
      h2s[n * 72 + ej] = f2bf(h);
      if (step == TWIN - 1) out[(size_t)(n0 + n) * OUTC + HD + ej] = h;
    }
    __syncthreads();
  }
}

// skip connection S -> out cols 128..141
__global__ __launch_bounds__(256) void k_out_s(const float* __restrict__ x,
                                               float* __restrict__ out) {
  int idx = blockIdx.x * 256 + threadIdx.x;
  if (idx < NODES * 14) {
    int n = idx / 14, c = idx - n * 14;
    float v = (c < CIN) ? x[n * CIN + c]
                        : x[((c - (CIN - 1)) * NODES + n) * CIN + (CIN - 1)];
    out[(size_t)n * OUTC + 128 + c] = v;
  }
}

extern "C" void kernel_launch(void* const* d_in, const int* in_sizes, int n_in,
                              void* d_out, int out_size, void* d_ws, size_t ws_size,
                              hipStream_t stream) {
  const float* x      = (const float*)d_in[0];
  const int*   ei     = (const int*)d_in[1];
  const float* ew     = (const float*)d_in[2];
  const float* W1     = (const float*)d_in[3];
  const float* b1     = (const float*)d_in[4];
  const float* W2     = (const float*)d_in[5];
  const float* b2     = (const float*)d_in[6];
  const float* gamma1 = (const float*)d_in[7];
  const float* beta1  = (const float*)d_in[8];
  const float* gamma2 = (const float*)d_in[9];
  const float* beta2  = (const float*)d_in[10];
  const float* Wih1   = (const float*)d_in[11];
  const float* Whh1   = (const float*)d_in[12];
  const float* bih1   = (const float*)d_in[13];
  const float* bhh1   = (const float*)d_in[14];
  const float* Wih2   = (const float*)d_in[15];
  const float* Whh2   = (const float*)d_in[16];
  const float* bih2   = (const float*)d_in[17];
  const float* bhh2   = (const float*)d_in[18];
  const int* srcI = ei;
  const int* dstI = ei + NE;
  float* out = (float*)d_out;

  char* base = (char*)d_ws;
  size_t off = 0;
  auto alloc = [&](size_t bytes) -> void* {
    void* p = base + off;
    off = (off + bytes + 255) & ~(size_t)255;
    return p;
  };
  // persistent small
  float* deg    = (float*)alloc(N_TOT * 4);
  float* dinv   = (float*)alloc(N_TOT * 4);
  int*   rowptr = (int*)alloc((N_TOT + 1) * 4);
  int*   bsum   = (int*)alloc(NB_SCAN * 4);
  ushort* Wp1   = (ushort*)alloc(32768 * 2);   // [4kc][16nt][64][8]
  ushort* Wphh1 = (ushort*)alloc(16384 * 2);   // [2kc][16nt][64][8]
  ushort* Wpih2 = (ushort*)alloc(16384 * 2);
  ushort* Wphh2 = (ushort*)alloc(16384 * 2);
  float* bsum1  = (float*)alloc(256 * 4);
  float* bsum2  = (float*)alloc(256 * 4);
  float* scale1 = (float*)alloc(HD * 4);
  float* shift1 = (float*)alloc(HD * 4);
  float* scale2 = (float*)alloc(HD * 4);
  float* shift2 = (float*)alloc(HD * 4);
  // zeroed-every-call region (contiguous)
  char* zstart = base + off;
  int*   cnt    = (int*)alloc(N_TOT * 4);
  int*   cursor = (int*)alloc(N_TOT * 4);
  float* sum1   = (float*)alloc(HD * 4);
  float* sq1    = (float*)alloc(HD * 4);
  float* sum2   = (float*)alloc(HD * 4);
  float* sq2    = (float*)alloc(HD * 4);
  size_t zbytes = (size_t)((base + off) - zstart);
  // big buffers
  int*   colA = (int*)alloc((size_t)NE * 4);
  float* valA = (float*)alloc((size_t)NE * 4);
  float* H0   = (float*)alloc((size_t)N_TOT * HD * 4);
  float* A1   = (float*)alloc((size_t)N_TOT * HD * 4);
  float* A2   = (float*)alloc((size_t)N_TOT * HD * 4);

  hipMemsetAsync(zstart, 0, zbytes, stream);
  k_init_deg<<<(N_TOT + 255) / 256, 256, 0, stream>>>(deg);
  k_pack<<<(32768 + 255) / 256, 256, 0, stream>>>(Wih1, Wp1, 128);
  k_pack<<<(16384 + 255) / 256, 256, 0, stream>>>(Whh1, Wphh1, 64);
  k_pack<<<(16384 + 255) / 256, 256, 0, stream>>>(Wih2, Wpih2, 64);
  k_pack<<<(16384 + 255) / 256, 256, 0, stream>>>(Whh2, Wphh2, 64);
  k_bsum<<<2, 256, 0, stream>>>(bih1, bhh1, bih2, bhh2, bsum1, bsum2);
  k_deg_cnt<<<(NE + 255) / 256, 256, 0, stream>>>(srcI, dstI, ew, deg, cnt);
  k_dinv<<<(N_TOT + 255) / 256, 256, 0, stream>>>(deg, dinv);
  k_scan_a<<<NB_SCAN, 256, 0, stream>>>(cnt, bsum, N_TOT);
  k_scan_b<<<1, 64, 0, stream>>>(bsum, NB_SCAN);
  k_scan_c<<<NB_SCAN, 256, 0, stream>>>(cnt, bsum, rowptr, N_TOT, NE);
  k_fill<<<(NE + 255) / 256, 256, 0, stream>>>(srcI, dstI, ew, dinv, rowptr, cursor, colA, valA);
  k_gemm_in<<<512, 256, 0, stream>>>(x, W1, H0);
  k_spmm<<<1024, 256, 0, stream>>>(H0, dinv, rowptr, colA, valA, b1, A1, sum1, sq1);
  k_bnfin<<<1, 64, 0, stream>>>(sum1, sq1, gamma1, beta1, scale1, shift1);
  k_gemm_h<<<512, 256, 0, stream>>>(A1, scale1, shift1, W2, H0);
  k_spmm<<<1024, 256, 0, stream>>>(H0, dinv, rowptr, colA, valA, b2, A2, sum2, sq2);
  k_bnfin<<<1, 64, 0, stream>>>(sum2, sq2, gamma2, beta2, scale2, shift2);
  k_lstm2<<<NODES / 32, 256, 0, stream>>>(A1, A2, scale1, shift1, scale2, shift2,
                                          Wp1, Wphh1, Wpih2, Wphh2, bsum1, bsum2, out);
  k_out_s<<<(NODES * 14 + 255) / 256, 256, 0, stream>>>(x, out);
}